// Round 2
// baseline (1424.631 us; speedup 1.0000x reference)
//
#include <hip/hip_runtime.h>

#define T_TOK 32768
#define HDIM  512
#define IDIM  1024
#define NEXP  8
#define BM    64
#define KI    64

typedef float    f32x4 __attribute__((ext_vector_type(4)));
typedef _Float16 f16x8 __attribute__((ext_vector_type(8)));
typedef _Float16 f16x4 __attribute__((ext_vector_type(4)));

// ---------------------------------------------------------------------------
// Router: logits = x @ rw + rb ; top-2 ; softmax over the 2 ; bucket append.
// ---------------------------------------------------------------------------
__global__ __launch_bounds__(256) void router_kernel(
    const float* __restrict__ x, const float* __restrict__ rw,
    const float* __restrict__ rb, int* __restrict__ cnt,
    int* __restrict__ btok, float* __restrict__ bw)
{
    __shared__ float Wl[HDIM * NEXP];      // 16 KB
    __shared__ float xc[64 * 133];         // 34 KB
    __shared__ float part[4 * 64 * 8];     // 8 KB

    const int tid = threadIdx.x;
    const int t0  = blockIdx.x * 64;

    for (int j = tid; j < HDIM * NEXP / 4; j += 256)
        ((float4*)Wl)[j] = ((const float4*)rw)[j];

    const int tl = tid & 63;
    const int q  = tid >> 6;

    float acc[8];
#pragma unroll
    for (int e = 0; e < 8; ++e) acc[e] = 0.f;

    for (int hc = 0; hc < 4; ++hc) {
        __syncthreads();
        for (int j = tid; j < 64 * 128 / 4; j += 256) {
            int row = j >> 5;
            int col = (j & 31) * 4;
            float4 v = *(const float4*)(x + (size_t)(t0 + row) * HDIM + hc * 128 + col);
            float* d = &xc[row * 133 + col];
            d[0] = v.x; d[1] = v.y; d[2] = v.z; d[3] = v.w;
        }
        __syncthreads();
#pragma unroll
        for (int hh = 0; hh < 32; ++hh) {
            int h = q * 32 + hh;
            float xv = xc[tl * 133 + h];
            const float* wrow = &Wl[(hc * 128 + h) * 8];
#pragma unroll
            for (int e = 0; e < 8; ++e) acc[e] += xv * wrow[e];
        }
    }
#pragma unroll
    for (int e = 0; e < 8; ++e) part[(q * 64 + tl) * 8 + e] = acc[e];
    __syncthreads();

    if (tid < 64) {
        float lg[8];
#pragma unroll
        for (int e = 0; e < 8; ++e)
            lg[e] = part[(0 * 64 + tid) * 8 + e] + part[(1 * 64 + tid) * 8 + e] +
                    part[(2 * 64 + tid) * 8 + e] + part[(3 * 64 + tid) * 8 + e] + rb[e];
        int e0 = 0;
#pragma unroll
        for (int e = 1; e < 8; ++e) if (lg[e] > lg[e0]) e0 = e;
        int e1 = (e0 == 0) ? 1 : 0;
#pragma unroll
        for (int e = 0; e < 8; ++e) if (e != e0 && lg[e] > lg[e1]) e1 = e;
        float z  = __expf(lg[e1] - lg[e0]);
        float w0 = 1.f / (1.f + z);
        float w1 = z * w0;
        int t = t0 + tid;
        int s0 = atomicAdd(&cnt[e0], 1);
        btok[e0 * T_TOK + s0] = t;  bw[e0 * T_TOK + s0] = w0;
        int s1 = atomicAdd(&cnt[e1], 1);
        btok[e1 * T_TOK + s1] = t;  bw[e1 * T_TOK + s1] = w1;
    }
}

// ---------------------------------------------------------------------------
// Transpose + fp32->fp16 convert: src [E][R][C] f32 -> dst [E][C][R] f16
// Vectorized: float4 reads, 8B packed f16 writes.
// ---------------------------------------------------------------------------
template <int R, int C>
__global__ __launch_bounds__(256) void transpose_cvt(
    const float* __restrict__ src, _Float16* __restrict__ dst)
{
    __shared__ float tile[32][33];
    const int e  = blockIdx.z;
    const int rb = blockIdx.y * 32, cb = blockIdx.x * 32;
    const int t  = threadIdx.x;
    {
        const int lr = t >> 3, lc = (t & 7) * 4;
        float4 v = *(const float4*)(src + ((size_t)e * R + rb + lr) * C + cb + lc);
        tile[lr][lc + 0] = v.x; tile[lr][lc + 1] = v.y;
        tile[lr][lc + 2] = v.z; tile[lr][lc + 3] = v.w;
    }
    __syncthreads();
    {
        const int c = t >> 3, r4 = (t & 7) * 4;
        f16x4 h;
        h[0] = (_Float16)tile[r4 + 0][c];
        h[1] = (_Float16)tile[r4 + 1][c];
        h[2] = (_Float16)tile[r4 + 2][c];
        h[3] = (_Float16)tile[r4 + 3][c];
        *(f16x4*)(dst + ((size_t)e * C + cb + c) * R + rb + r4) = h;
    }
}

// ---------------------------------------------------------------------------
// Fused expert kernel. Block = (expert e, 64 bucket rows), 512 threads.
// LDS 74 KB -> 2 blocks/CU (16 waves/CU). KI=64 chunks.
// Phase1 wave (wm=wv>>2, wn=wv&3): rows wm*32+[0,32), gate/up cols wn*16+[0,16).
// Phase2 wave: rows wm*32+[0,32), out cols wn*128+[0,128).
// ---------------------------------------------------------------------------
__global__ __launch_bounds__(512, 4) void moe_kernel(
    const float* __restrict__ x,
    const _Float16* __restrict__ wgu_t,   // [E][2I][H]
    const float* __restrict__ bgu,        // [E][2I]
    const _Float16* __restrict__ wd_t,    // [E][H][I]
    const float* __restrict__ bd,         // [E][H]
    const int* __restrict__ cnt,
    const int* __restrict__ btok,
    const float* __restrict__ bw,
    float* __restrict__ out)
{
    const int e   = blockIdx.y;
    const int n_e = cnt[e];
    const int m0  = blockIdx.x * BM;
    if (m0 >= n_e) return;

    __shared__ __align__(16) _Float16 A[BM * HDIM];    // 64 KB, XOR-swizzled
    __shared__ __align__(16) _Float16 ACT[BM * KI];    // 8 KB, XOR-swizzled
    __shared__ int   s_tok[BM];
    __shared__ float s_w[BM];

    const int tid  = threadIdx.x;
    const int lane = tid & 63;
    const int wv   = tid >> 6;
    const int wm   = wv >> 2;             // 0..1  (row half)
    const int wn   = wv & 3;              // 0..3  (col quarter)
    const int bn   = lane & 15;
    const int bk   = (lane >> 4) * 8;

    if (tid < BM) {
        int idx = m0 + tid;
        if (idx < n_e) { s_tok[tid] = btok[e * T_TOK + idx]; s_w[tid] = bw[e * T_TOK + idx]; }
        else           { s_tok[tid] = -1;                    s_w[tid] = 0.f; }
    }
    __syncthreads();

    // ---- gather x rows -> fp16 swizzled LDS (8 threads per row) ----
    {
        const int r  = tid >> 3;
        const int tk = s_tok[r];
#pragma unroll
        for (int j = 0; j < 8; ++j) {
            const int c = ((tid & 7) + j * 8) * 8;
            float4 f0, f1;
            if (tk >= 0) {
                const float4* p = (const float4*)(x + (size_t)tk * HDIM + c);
                f0 = p[0]; f1 = p[1];
            } else { f0 = make_float4(0, 0, 0, 0); f1 = f0; }
            f16x8 h;
            h[0] = (_Float16)f0.x; h[1] = (_Float16)f0.y;
            h[2] = (_Float16)f0.z; h[3] = (_Float16)f0.w;
            h[4] = (_Float16)f1.x; h[5] = (_Float16)f1.y;
            h[6] = (_Float16)f1.z; h[7] = (_Float16)f1.w;
            int byte = r * 1024 + c * 2;  byte ^= (r & 7) << 4;
            *(f16x8*)((char*)A + byte) = h;
        }
    }
    __syncthreads();

    f32x4 accO[2][8];
#pragma unroll
    for (int mt = 0; mt < 2; ++mt)
#pragma unroll
        for (int nt = 0; nt < 8; ++nt)
#pragma unroll
            for (int r = 0; r < 4; ++r) accO[mt][nt][r] = 0.f;

    for (int ic = 0; ic < IDIM / KI; ++ic) {
        // ------------------ phase 1: gate & up (16 cols each per wave) ------
        f32x4 accG[2], accU[2];
#pragma unroll
        for (int mt = 0; mt < 2; ++mt)
#pragma unroll
            for (int r = 0; r < 4; ++r) { accG[mt][r] = 0.f; accU[mt][r] = 0.f; }

        const _Float16* bg = wgu_t + ((size_t)(e * 2 * IDIM) + ic * KI + wn * 16 + bn) * HDIM;
        const _Float16* bu = bg + (size_t)IDIM * HDIM;

#pragma unroll 4
        for (int ks = 0; ks < 16; ++ks) {
            const int k0 = ks * 32 + bk;
            f16x8 bgf = *(const f16x8*)(bg + k0);
            f16x8 buf = *(const f16x8*)(bu + k0);
#pragma unroll
            for (int mt = 0; mt < 2; ++mt) {
                const int m = wm * 32 + mt * 16 + bn;
                int byte = m * 1024 + k0 * 2;  byte ^= (m & 7) << 4;
                f16x8 af = *(const f16x8*)((const char*)A + byte);
                accG[mt] = __builtin_amdgcn_mfma_f32_16x16x32_f16(af, bgf, accG[mt], 0, 0, 0);
                accU[mt] = __builtin_amdgcn_mfma_f32_16x16x32_f16(af, buf, accU[mt], 0, 0, 0);
            }
        }
        // bias + quick_gelu -> ACT
        const int   gidx = e * 2 * IDIM + ic * KI + wn * 16 + bn;
        const float bgv  = bgu[gidx];
        const float buv  = bgu[gidx + IDIM];
#pragma unroll
        for (int mt = 0; mt < 2; ++mt) {
#pragma unroll
            for (int r = 0; r < 4; ++r) {
                float g = accG[mt][r] + bgv;
                float u = accU[mt][r] + buv;
                float a = (u + 1.f) * g / (1.f + __expf(-1.702f * g));
                const int row = wm * 32 + mt * 16 + ((lane >> 4) << 2) + r;
                const int col = wn * 16 + bn;
                int byte = row * 128 + col * 2;  byte ^= (row & 7) << 4;
                *(_Float16*)((char*)ACT + byte) = (_Float16)a;
            }
        }
        __syncthreads();

        // ------------------ phase 2: down-proj accumulate -------------------
#pragma unroll
        for (int ks = 0; ks < 2; ++ks) {
            const int kl = ks * 32 + bk;
            const int kg = ic * KI + kl;
            f16x8 af2[2];
#pragma unroll
            for (int mt = 0; mt < 2; ++mt) {
                const int m = wm * 32 + mt * 16 + bn;
                int byte = m * 128 + kl * 2;  byte ^= (m & 7) << 4;
                af2[mt] = *(const f16x8*)((const char*)ACT + byte);
            }
#pragma unroll
            for (int ng = 0; ng < 2; ++ng) {
                f16x8 bf[4];
#pragma unroll
                for (int nq = 0; nq < 4; ++nq) {
                    const int hcol = wn * 128 + (ng * 4 + nq) * 16 + bn;
                    bf[nq] = *(const f16x8*)(wd_t + ((size_t)(e * HDIM) + hcol) * IDIM + kg);
                }
#pragma unroll
                for (int mt = 0; mt < 2; ++mt)
#pragma unroll
                    for (int nq = 0; nq < 4; ++nq)
                        accO[mt][ng * 4 + nq] = __builtin_amdgcn_mfma_f32_16x16x32_f16(
                            af2[mt], bf[nq], accO[mt][ng * 4 + nq], 0, 0, 0);
            }
        }
        __syncthreads();
    }

    // ------------------ epilogue: weighted atomic scatter -------------------
    float bdv[8];
#pragma unroll
    for (int nt = 0; nt < 8; ++nt) bdv[nt] = bd[e * HDIM + wn * 128 + nt * 16 + bn];
#pragma unroll
    for (int mt = 0; mt < 2; ++mt) {
#pragma unroll
        for (int r = 0; r < 4; ++r) {
            const int m  = wm * 32 + mt * 16 + ((lane >> 4) << 2) + r;
            const int tk = s_tok[m];
            if (tk < 0) continue;
            const float wgt = s_w[m];
            float* orow = out + (size_t)tk * HDIM + wn * 128 + bn;
#pragma unroll
            for (int nt = 0; nt < 8; ++nt)
                atomicAdd(orow + nt * 16, (accO[mt][nt][r] + bdv[nt]) * wgt);
        }
    }
}

// ---------------------------------------------------------------------------
extern "C" void kernel_launch(void* const* d_in, const int* in_sizes, int n_in,
                              void* d_out, int out_size, void* d_ws, size_t ws_size,
                              hipStream_t stream)
{
    const float* x   = (const float*)d_in[0];
    const float* rw  = (const float*)d_in[1];
    const float* rb  = (const float*)d_in[2];
    const float* wgu = (const float*)d_in[3];
    const float* bgu = (const float*)d_in[4];
    const float* wd  = (const float*)d_in[5];
    const float* bd  = (const float*)d_in[6];
    float* out = (float*)d_out;

    char* ws = (char*)d_ws;
    size_t o = 0;
    int*   cnt  = (int*)(ws + o);   o += 256;
    int*   btok = (int*)(ws + o);   o += (size_t)NEXP * T_TOK * 4;
    float* bwp  = (float*)(ws + o); o += (size_t)NEXP * T_TOK * 4;
    _Float16* wgu_t = (_Float16*)(ws + o); o += (size_t)NEXP * 2 * IDIM * HDIM * 2;
    _Float16* wd_t  = (_Float16*)(ws + o); o += (size_t)NEXP * HDIM * IDIM * 2;

    hipMemsetAsync(cnt, 0, 256, stream);
    hipMemsetAsync(out, 0, (size_t)out_size * 4, stream);

    transpose_cvt<HDIM, 2 * IDIM><<<dim3(2 * IDIM / 32, HDIM / 32, NEXP), 256, 0, stream>>>(wgu, wgu_t);
    transpose_cvt<IDIM, HDIM><<<dim3(HDIM / 32, IDIM / 32, NEXP), 256, 0, stream>>>(wd, wd_t);
    router_kernel<<<T_TOK / 64, 256, 0, stream>>>(x, rw, rb, cnt, btok, bwp);
    moe_kernel<<<dim3(T_TOK / BM, NEXP), 512, 0, stream>>>(
        x, wgu_t, bgu, wd_t, bd, cnt, btok, bwp, out);
}

// Round 3
// 773.355 us; speedup vs baseline: 1.8421x; 1.8421x over previous
//
#include <hip/hip_runtime.h>

#define T_TOK 32768
#define HDIM  512
#define IDIM  1024
#define NEXP  8
#define BM    64
#define KI    128

typedef float    f32x4 __attribute__((ext_vector_type(4)));
typedef _Float16 f16x8 __attribute__((ext_vector_type(8)));
typedef _Float16 f16x4 __attribute__((ext_vector_type(4)));

// ---------------------------------------------------------------------------
// Router: logits = x @ rw + rb ; top-2 ; softmax over the 2 ; bucket append.
// Block-aggregated bucket atomics: LDS counts, ONE global atomic per expert
// per block (bucket order is irrelevant — combine is additive).
// ---------------------------------------------------------------------------
__global__ __launch_bounds__(256) void router_kernel(
    const float* __restrict__ x, const float* __restrict__ rw,
    const float* __restrict__ rb, int* __restrict__ cnt,
    int* __restrict__ btok, float* __restrict__ bw)
{
    __shared__ float Wl[HDIM * NEXP];      // 16 KB
    __shared__ float xc[64 * 133];         // 34 KB
    __shared__ float part[4 * 64 * 8];     // 8 KB
    __shared__ int   bcnt[NEXP];
    __shared__ int   sbase[NEXP];

    const int tid = threadIdx.x;
    const int t0  = blockIdx.x * 64;

    if (tid < NEXP) bcnt[tid] = 0;

    for (int j = tid; j < HDIM * NEXP / 4; j += 256)
        ((float4*)Wl)[j] = ((const float4*)rw)[j];

    const int tl = tid & 63;
    const int q  = tid >> 6;

    float acc[8];
#pragma unroll
    for (int e = 0; e < 8; ++e) acc[e] = 0.f;

    for (int hc = 0; hc < 4; ++hc) {
        __syncthreads();
        for (int j = tid; j < 64 * 128 / 4; j += 256) {
            int row = j >> 5;
            int col = (j & 31) * 4;
            float4 v = *(const float4*)(x + (size_t)(t0 + row) * HDIM + hc * 128 + col);
            float* d = &xc[row * 133 + col];
            d[0] = v.x; d[1] = v.y; d[2] = v.z; d[3] = v.w;
        }
        __syncthreads();
#pragma unroll
        for (int hh = 0; hh < 32; ++hh) {
            int h = q * 32 + hh;
            float xv = xc[tl * 133 + h];
            const float* wrow = &Wl[(hc * 128 + h) * 8];
#pragma unroll
            for (int e = 0; e < 8; ++e) acc[e] += xv * wrow[e];
        }
    }
#pragma unroll
    for (int e = 0; e < 8; ++e) part[(q * 64 + tl) * 8 + e] = acc[e];
    __syncthreads();

    int e0 = 0, e1 = 0, l0 = 0, l1 = 0;
    float w0 = 0.f, w1 = 0.f;
    if (tid < 64) {
        float lg[8];
#pragma unroll
        for (int e = 0; e < 8; ++e)
            lg[e] = part[(0 * 64 + tid) * 8 + e] + part[(1 * 64 + tid) * 8 + e] +
                    part[(2 * 64 + tid) * 8 + e] + part[(3 * 64 + tid) * 8 + e] + rb[e];
#pragma unroll
        for (int e = 1; e < 8; ++e) if (lg[e] > lg[e0]) e0 = e;
        e1 = (e0 == 0) ? 1 : 0;
#pragma unroll
        for (int e = 0; e < 8; ++e) if (e != e0 && lg[e] > lg[e1]) e1 = e;
        float z = __expf(lg[e1] - lg[e0]);
        w0 = 1.f / (1.f + z);
        w1 = z * w0;
        l0 = atomicAdd(&bcnt[e0], 1);      // LDS atomic
        l1 = atomicAdd(&bcnt[e1], 1);
    }
    __syncthreads();
    if (tid < NEXP) sbase[tid] = atomicAdd(&cnt[tid], bcnt[tid]);
    __syncthreads();
    if (tid < 64) {
        int t  = t0 + tid;
        int s0 = sbase[e0] + l0;
        btok[e0 * T_TOK + s0] = t;  bw[e0 * T_TOK + s0] = w0;
        int s1 = sbase[e1] + l1;
        btok[e1 * T_TOK + s1] = t;  bw[e1 * T_TOK + s1] = w1;
    }
}

// ---------------------------------------------------------------------------
// Transpose + fp32->fp16 convert: src [E][R][C] f32 -> dst [E][C][R] f16
// ---------------------------------------------------------------------------
template <int R, int C>
__global__ __launch_bounds__(256) void transpose_cvt(
    const float* __restrict__ src, _Float16* __restrict__ dst)
{
    __shared__ float tile[32][33];
    const int e  = blockIdx.z;
    const int rb = blockIdx.y * 32, cb = blockIdx.x * 32;
    const int t  = threadIdx.x;
    {
        const int lr = t >> 3, lc = (t & 7) * 4;
        float4 v = *(const float4*)(src + ((size_t)e * R + rb + lr) * C + cb + lc);
        tile[lr][lc + 0] = v.x; tile[lr][lc + 1] = v.y;
        tile[lr][lc + 2] = v.z; tile[lr][lc + 3] = v.w;
    }
    __syncthreads();
    {
        const int c = t >> 3, r4 = (t & 7) * 4;
        f16x4 h;
        h[0] = (_Float16)tile[r4 + 0][c];
        h[1] = (_Float16)tile[r4 + 1][c];
        h[2] = (_Float16)tile[r4 + 2][c];
        h[3] = (_Float16)tile[r4 + 3][c];
        *(f16x4*)(dst + ((size_t)e * C + cb + c) * R + rb + r4) = h;
    }
}

// ---------------------------------------------------------------------------
// Fused expert kernel (round-1 geometry + expert<->XCD affinity + ACT dbuf).
// Block = (expert e = bid&7 -> XCD e, 64 bucket rows), 512 threads, 8 waves.
// Each XCD's L2 (4MB) then holds exactly one expert's fp16 weights (3MB).
// Per 128-wide I-chunk: phase1 gate/up MFMA -> ACT[ic&1]; ONE barrier;
// phase2 down-proj MFMA accumulate. Epilogue: weighted atomic scatter.
// ---------------------------------------------------------------------------
__global__ __launch_bounds__(512) void moe_kernel(
    const float* __restrict__ x,
    const _Float16* __restrict__ wgu_t,   // [E][2I][H]
    const float* __restrict__ bgu,        // [E][2I]
    const _Float16* __restrict__ wd_t,    // [E][H][I]
    const float* __restrict__ bd,         // [E][H]
    const int* __restrict__ cnt,
    const int* __restrict__ btok,
    const float* __restrict__ bw,
    float* __restrict__ out)
{
    const int bid = blockIdx.x;
    const int e   = bid & 7;              // XCD affinity: XCD = bid % 8
    const int m0  = (bid >> 3) * BM;
    const int n_e = cnt[e];
    if (m0 >= n_e) return;

    __shared__ __align__(16) _Float16 A[BM * HDIM];       // 64 KB, XOR-swizzled
    __shared__ __align__(16) _Float16 ACT[2][BM * KI];    // 2 x 16 KB, swizzled
    __shared__ int   s_tok[BM];
    __shared__ float s_w[BM];

    const int tid  = threadIdx.x;
    const int lane = tid & 63;
    const int wv   = tid >> 6;            // 0..7
    const int bn   = lane & 15;
    const int bk   = (lane >> 4) * 8;

    if (tid < BM) {
        int idx = m0 + tid;
        if (idx < n_e) { s_tok[tid] = btok[e * T_TOK + idx]; s_w[tid] = bw[e * T_TOK + idx]; }
        else           { s_tok[tid] = -1;                    s_w[tid] = 0.f; }
    }
    __syncthreads();

    // ---- gather x rows -> fp16 swizzled LDS (8 threads per row) ----
    {
        const int r  = tid >> 3;
        const int tk = s_tok[r];
#pragma unroll
        for (int j = 0; j < 8; ++j) {
            const int c = ((tid & 7) + j * 8) * 8;
            float4 f0, f1;
            if (tk >= 0) {
                const float4* p = (const float4*)(x + (size_t)tk * HDIM + c);
                f0 = p[0]; f1 = p[1];
            } else { f0 = make_float4(0, 0, 0, 0); f1 = f0; }
            f16x8 h;
            h[0] = (_Float16)f0.x; h[1] = (_Float16)f0.y;
            h[2] = (_Float16)f0.z; h[3] = (_Float16)f0.w;
            h[4] = (_Float16)f1.x; h[5] = (_Float16)f1.y;
            h[6] = (_Float16)f1.z; h[7] = (_Float16)f1.w;
            int byte = r * 1024 + c * 2;  byte ^= (r & 7) << 4;
            *(f16x8*)((char*)A + byte) = h;
        }
    }
    __syncthreads();

    f32x4 accO[4][4];
#pragma unroll
    for (int mt = 0; mt < 4; ++mt)
#pragma unroll
        for (int nt = 0; nt < 4; ++nt)
#pragma unroll
            for (int r = 0; r < 4; ++r) accO[mt][nt][r] = 0.f;

    for (int ic = 0; ic < IDIM / KI; ++ic) {
        char* actb = (char*)ACT + (ic & 1) * (BM * KI * 2);

        // ------------------ phase 1: gate & up ------------------
        f32x4 accG[4], accU[4];
#pragma unroll
        for (int mt = 0; mt < 4; ++mt)
#pragma unroll
            for (int r = 0; r < 4; ++r) { accG[mt][r] = 0.f; accU[mt][r] = 0.f; }

        const _Float16* bg = wgu_t + ((size_t)(e * 2 * IDIM) + ic * KI + wv * 16 + bn) * HDIM;
        const _Float16* bu = bg + (size_t)IDIM * HDIM;

#pragma unroll
        for (int ks = 0; ks < 16; ++ks) {
            const int k0 = ks * 32 + bk;
            f16x8 bgf = *(const f16x8*)(bg + k0);
            f16x8 buf = *(const f16x8*)(bu + k0);
#pragma unroll
            for (int mt = 0; mt < 4; ++mt) {
                const int m = mt * 16 + bn;
                int byte = m * 1024 + k0 * 2;  byte ^= (m & 7) << 4;
                f16x8 af = *(const f16x8*)((const char*)A + byte);
                accG[mt] = __builtin_amdgcn_mfma_f32_16x16x32_f16(af, bgf, accG[mt], 0, 0, 0);
                accU[mt] = __builtin_amdgcn_mfma_f32_16x16x32_f16(af, buf, accU[mt], 0, 0, 0);
            }
        }
        // bias + quick_gelu -> ACT[ic&1]
        const int   gidx = e * 2 * IDIM + ic * KI + wv * 16 + bn;
        const float bgv  = bgu[gidx];
        const float buv  = bgu[gidx + IDIM];
#pragma unroll
        for (int mt = 0; mt < 4; ++mt) {
#pragma unroll
            for (int r = 0; r < 4; ++r) {
                float g = accG[mt][r] + bgv;
                float u = accU[mt][r] + buv;
                float a = (u + 1.f) * g / (1.f + __expf(-1.702f * g));
                const int row = mt * 16 + ((lane >> 4) << 2) + r;
                const int col = wv * 16 + bn;
                int byte = row * 256 + col * 2;  byte ^= (row & 7) << 4;
                *(_Float16*)(actb + byte) = (_Float16)a;
            }
        }
        __syncthreads();   // the ONLY barrier per ic (ACT is double-buffered)

        // ------------------ phase 2: down-proj accumulate -------------------
        const _Float16* bdp = wd_t + ((size_t)(e * HDIM) + wv * 64) * IDIM;
#pragma unroll
        for (int ks = 0; ks < 4; ++ks) {
            const int kl = ks * 32 + bk;
            const int kg = ic * KI + kl;
            f16x8 bf[4];
#pragma unroll
            for (int nt = 0; nt < 4; ++nt)
                bf[nt] = *(const f16x8*)(bdp + (size_t)(nt * 16 + bn) * IDIM + kg);
#pragma unroll
            for (int mt = 0; mt < 4; ++mt) {
                const int m = mt * 16 + bn;
                int byte = m * 256 + kl * 2;  byte ^= (m & 7) << 4;
                f16x8 af = *(const f16x8*)((const char*)actb + byte);
#pragma unroll
                for (int nt = 0; nt < 4; ++nt)
                    accO[mt][nt] = __builtin_amdgcn_mfma_f32_16x16x32_f16(af, bf[nt], accO[mt][nt], 0, 0, 0);
            }
        }
        // no trailing barrier: next phase1 writes the other ACT buffer
    }

    // ------------------ epilogue: weighted atomic scatter -------------------
    float bdv[4];
#pragma unroll
    for (int nt = 0; nt < 4; ++nt) bdv[nt] = bd[e * HDIM + wv * 64 + nt * 16 + bn];
#pragma unroll
    for (int mt = 0; mt < 4; ++mt) {
#pragma unroll
        for (int r = 0; r < 4; ++r) {
            const int m  = mt * 16 + ((lane >> 4) << 2) + r;
            const int tk = s_tok[m];
            if (tk < 0) continue;
            const float wgt = s_w[m];
            float* orow = out + (size_t)tk * HDIM + wv * 64 + bn;
#pragma unroll
            for (int nt = 0; nt < 4; ++nt)
                atomicAdd(orow + nt * 16, (accO[mt][nt][r] + bdv[nt]) * wgt);
        }
    }
}

// ---------------------------------------------------------------------------
extern "C" void kernel_launch(void* const* d_in, const int* in_sizes, int n_in,
                              void* d_out, int out_size, void* d_ws, size_t ws_size,
                              hipStream_t stream)
{
    const float* x   = (const float*)d_in[0];
    const float* rw  = (const float*)d_in[1];
    const float* rb  = (const float*)d_in[2];
    const float* wgu = (const float*)d_in[3];
    const float* bgu = (const float*)d_in[4];
    const float* wd  = (const float*)d_in[5];
    const float* bd  = (const float*)d_in[6];
    float* out = (float*)d_out;

    char* ws = (char*)d_ws;
    size_t o = 0;
    int*   cnt  = (int*)(ws + o);   o += 256;
    int*   btok = (int*)(ws + o);   o += (size_t)NEXP * T_TOK * 4;
    float* bwp  = (float*)(ws + o); o += (size_t)NEXP * T_TOK * 4;
    _Float16* wgu_t = (_Float16*)(ws + o); o += (size_t)NEXP * 2 * IDIM * HDIM * 2;
    _Float16* wd_t  = (_Float16*)(ws + o); o += (size_t)NEXP * HDIM * IDIM * 2;

    hipMemsetAsync(cnt, 0, 256, stream);
    hipMemsetAsync(out, 0, (size_t)out_size * 4, stream);

    transpose_cvt<HDIM, 2 * IDIM><<<dim3(2 * IDIM / 32, HDIM / 32, NEXP), 256, 0, stream>>>(wgu, wgu_t);
    transpose_cvt<IDIM, HDIM><<<dim3(HDIM / 32, IDIM / 32, NEXP), 256, 0, stream>>>(wd, wd_t);
    router_kernel<<<T_TOK / 64, 256, 0, stream>>>(x, rw, rb, cnt, btok, bwp);
    moe_kernel<<<dim3((T_TOK / BM) * NEXP), 512, 0, stream>>>(
        x, wgu_t, bgu, wd_t, bd, cnt, btok, bwp, out);
}

// Round 4
// 748.154 us; speedup vs baseline: 1.9042x; 1.0337x over previous
//
#include <hip/hip_runtime.h>

#define T_TOK 32768
#define HDIM  512
#define IDIM  1024
#define NEXP  8
#define BM    64
#define KI    128

typedef float    f32x4 __attribute__((ext_vector_type(4)));
typedef _Float16 f16x8 __attribute__((ext_vector_type(8)));
typedef _Float16 f16x4 __attribute__((ext_vector_type(4)));

// global_load_lds, 16B per lane, LDS dest = wave-uniform base + lane*16
#define GL2LDS(gp, lp)                                                        \
    __builtin_amdgcn_global_load_lds(                                         \
        (const __attribute__((address_space(1))) void*)(gp),                  \
        (__attribute__((address_space(3))) void*)(lp), 16, 0, 0)

// ---------------------------------------------------------------------------
// Router: logits = x @ rw + rb ; top-2 ; softmax over the 2 ; bucket append.
// Block-aggregated bucket atomics (LDS counts, 8 global atomics per block).
// ---------------------------------------------------------------------------
__global__ __launch_bounds__(256) void router_kernel(
    const float* __restrict__ x, const float* __restrict__ rw,
    const float* __restrict__ rb, int* __restrict__ cnt,
    int* __restrict__ btok, float* __restrict__ bw)
{
    __shared__ float Wl[HDIM * NEXP];
    __shared__ float xc[64 * 133];
    __shared__ float part[4 * 64 * 8];
    __shared__ int   bcnt[NEXP];
    __shared__ int   sbase[NEXP];

    const int tid = threadIdx.x;
    const int t0  = blockIdx.x * 64;

    if (tid < NEXP) bcnt[tid] = 0;

    for (int j = tid; j < HDIM * NEXP / 4; j += 256)
        ((float4*)Wl)[j] = ((const float4*)rw)[j];

    const int tl = tid & 63;
    const int q  = tid >> 6;

    float acc[8];
#pragma unroll
    for (int e = 0; e < 8; ++e) acc[e] = 0.f;

    for (int hc = 0; hc < 4; ++hc) {
        __syncthreads();
        for (int j = tid; j < 64 * 128 / 4; j += 256) {
            int row = j >> 5;
            int col = (j & 31) * 4;
            float4 v = *(const float4*)(x + (size_t)(t0 + row) * HDIM + hc * 128 + col);
            float* d = &xc[row * 133 + col];
            d[0] = v.x; d[1] = v.y; d[2] = v.z; d[3] = v.w;
        }
        __syncthreads();
#pragma unroll
        for (int hh = 0; hh < 32; ++hh) {
            int h = q * 32 + hh;
            float xv = xc[tl * 133 + h];
            const float* wrow = &Wl[(hc * 128 + h) * 8];
#pragma unroll
            for (int e = 0; e < 8; ++e) acc[e] += xv * wrow[e];
        }
    }
#pragma unroll
    for (int e = 0; e < 8; ++e) part[(q * 64 + tl) * 8 + e] = acc[e];
    __syncthreads();

    int e0 = 0, e1 = 0, l0 = 0, l1 = 0;
    float w0 = 0.f, w1 = 0.f;
    if (tid < 64) {
        float lg[8];
#pragma unroll
        for (int e = 0; e < 8; ++e)
            lg[e] = part[(0 * 64 + tid) * 8 + e] + part[(1 * 64 + tid) * 8 + e] +
                    part[(2 * 64 + tid) * 8 + e] + part[(3 * 64 + tid) * 8 + e] + rb[e];
#pragma unroll
        for (int e = 1; e < 8; ++e) if (lg[e] > lg[e0]) e0 = e;
        e1 = (e0 == 0) ? 1 : 0;
#pragma unroll
        for (int e = 0; e < 8; ++e) if (e != e0 && lg[e] > lg[e1]) e1 = e;
        float z = __expf(lg[e1] - lg[e0]);
        w0 = 1.f / (1.f + z);
        w1 = z * w0;
        l0 = atomicAdd(&bcnt[e0], 1);
        l1 = atomicAdd(&bcnt[e1], 1);
    }
    __syncthreads();
    if (tid < NEXP) sbase[tid] = atomicAdd(&cnt[tid], bcnt[tid]);
    __syncthreads();
    if (tid < 64) {
        int t  = t0 + tid;
        int s0 = sbase[e0] + l0;
        btok[e0 * T_TOK + s0] = t;  bw[e0 * T_TOK + s0] = w0;
        int s1 = sbase[e1] + l1;
        btok[e1 * T_TOK + s1] = t;  bw[e1 * T_TOK + s1] = w1;
    }
}

// ---------------------------------------------------------------------------
// Transpose + fp32->fp16 convert: src [E][R][C] f32 -> dst [E][C][R] f16
// ---------------------------------------------------------------------------
template <int R, int C>
__global__ __launch_bounds__(256) void transpose_cvt(
    const float* __restrict__ src, _Float16* __restrict__ dst)
{
    __shared__ float tile[32][33];
    const int e  = blockIdx.z;
    const int rb = blockIdx.y * 32, cb = blockIdx.x * 32;
    const int t  = threadIdx.x;
    {
        const int lr = t >> 3, lc = (t & 7) * 4;
        float4 v = *(const float4*)(src + ((size_t)e * R + rb + lr) * C + cb + lc);
        tile[lr][lc + 0] = v.x; tile[lr][lc + 1] = v.y;
        tile[lr][lc + 2] = v.z; tile[lr][lc + 3] = v.w;
    }
    __syncthreads();
    {
        const int c = t >> 3, r4 = (t & 7) * 4;
        f16x4 h;
        h[0] = (_Float16)tile[r4 + 0][c];
        h[1] = (_Float16)tile[r4 + 1][c];
        h[2] = (_Float16)tile[r4 + 2][c];
        h[3] = (_Float16)tile[r4 + 3][c];
        *(f16x4*)(dst + ((size_t)e * C + cb + c) * R + rb + r4) = h;
    }
}

// ---------------------------------------------------------------------------
// Fused expert kernel, staged-pipeline phase 1.
// Block = (expert e = bid&7 -> XCD e, 64 bucket rows), 512 threads, 8 waves.
// Phase1 per ic (128 gate+up cols): K-loop 16 steps of K=32; each step's
// 128col x 32k gate+up tile (16 KB) is DMA'd by global_load_lds into a
// double-buffered LDS tile one step ahead; barrier-per-step 2-phase schedule.
// BGU layout: col-unit = 128 B {gate 64B | up 64B}, read-swizzled by
// byte ^= ((byte>>7)&7)<<4 (involution; conflict-free b128 reads); the DMA
// dest is LINEAR (tid*16) and the global SOURCE is inverse-permuted (rule #21).
// ---------------------------------------------------------------------------
__global__ __launch_bounds__(512) void moe_kernel(
    const float* __restrict__ x,
    const _Float16* __restrict__ wgu_t,   // [E][2I][H]
    const float* __restrict__ bgu,        // [E][2I]
    const _Float16* __restrict__ wd_t,    // [E][H][I]
    const float* __restrict__ bd,         // [E][H]
    const int* __restrict__ cnt,
    const int* __restrict__ btok,
    const float* __restrict__ bw,
    float* __restrict__ out)
{
    const int bid = blockIdx.x;
    const int e   = bid & 7;              // XCD affinity
    const int m0  = (bid >> 3) * BM;
    const int n_e = cnt[e];
    if (m0 >= n_e) return;

    __shared__ __align__(16) _Float16 A[BM * HDIM];      // 64 KB, XOR-swizzled
    __shared__ __align__(16) _Float16 BGU[2 * 8192];     // 2 x 16 KB staged dbuf
    __shared__ __align__(16) _Float16 ACT[2][BM * KI];   // 2 x 16 KB, swizzled
    __shared__ int   s_tok[BM];
    __shared__ float s_w[BM];

    const int tid  = threadIdx.x;
    const int lane = tid & 63;
    const int wv   = tid >> 6;
    const int bn   = lane & 15;
    const int bk   = (lane >> 4) * 8;

    // --- per-thread stage source decode (two 16B granules per thread) ---
    // dest byte d -> unswizzled u -> (colu, isup, kbyte)
    const int d1 = tid * 16;
    const int u1 = d1 ^ (((d1 >> 7) & 7) << 4);
    const int d2 = d1 + 8192;
    const int u2 = d2 ^ (((d2 >> 7) & 7) << 4);
    const _Float16* wguE = wgu_t + (size_t)e * 2 * IDIM * HDIM;
    const _Float16* sp1  = wguE + ((size_t)(((u1 >> 6) & 1) * IDIM + (u1 >> 7))) * HDIM + ((u1 & 63) >> 1);
    const _Float16* sp2  = wguE + ((size_t)(((u2 >> 6) & 1) * IDIM + (u2 >> 7))) * HDIM + ((u2 & 63) >> 1);
    _Float16* lp1 = BGU + tid * 8;        // elements (= byte d1)
    _Float16* lp2 = lp1 + 4096;           // (= byte d2)

    if (tid < BM) {
        int idx = m0 + tid;
        if (idx < n_e) { s_tok[tid] = btok[e * T_TOK + idx]; s_w[tid] = bw[e * T_TOK + idx]; }
        else           { s_tok[tid] = -1;                    s_w[tid] = 0.f; }
    }
    __syncthreads();

    // stage (ic=0, ks=0) into buf0 — in flight during the A-gather
    GL2LDS(sp1, lp1);
    GL2LDS(sp2, lp2);

    // ---- gather x rows -> fp16 swizzled LDS (8 threads per row) ----
    {
        const int r  = tid >> 3;
        const int tk = s_tok[r];
#pragma unroll
        for (int j = 0; j < 8; ++j) {
            const int c = ((tid & 7) + j * 8) * 8;
            float4 f0, f1;
            if (tk >= 0) {
                const float4* p = (const float4*)(x + (size_t)tk * HDIM + c);
                f0 = p[0]; f1 = p[1];
            } else { f0 = make_float4(0, 0, 0, 0); f1 = f0; }
            f16x8 h;
            h[0] = (_Float16)f0.x; h[1] = (_Float16)f0.y;
            h[2] = (_Float16)f0.z; h[3] = (_Float16)f0.w;
            h[4] = (_Float16)f1.x; h[5] = (_Float16)f1.y;
            h[6] = (_Float16)f1.z; h[7] = (_Float16)f1.w;
            int byte = r * 1024 + c * 2;  byte ^= (r & 7) << 4;
            *(f16x8*)((char*)A + byte) = h;
        }
    }

    f32x4 accO[4][4];
#pragma unroll
    for (int mt = 0; mt < 4; ++mt)
#pragma unroll
        for (int nt = 0; nt < 4; ++nt)
#pragma unroll
            for (int r = 0; r < 4; ++r) accO[mt][nt][r] = 0.f;

    // B-frag read addresses (swizzled), fixed per thread
    const int colu = wv * 16 + bn;
    const int sw   = (colu & 7) << 4;
    const int bgOff = colu * 128 + ((bk * 2) ^ sw);          // gate frag byte
    const int buOff = colu * 128 + ((64 + bk * 2) ^ sw);     // up frag byte

    for (int ic = 0; ic < IDIM / KI; ++ic) {
        // ------------------ phase 1: gate & up, staged 2-phase --------------
        f32x4 accG[4], accU[4];
#pragma unroll
        for (int mt = 0; mt < 4; ++mt)
#pragma unroll
            for (int r = 0; r < 4; ++r) { accG[mt][r] = 0.f; accU[mt][r] = 0.f; }

        for (int ks = 0; ks < 16; ++ks) {
            __syncthreads();   // drains stage(ks) -> buf[ks&1] ready; also
                               // orders A-gather (ic=0,ks=0) / ACT dbuf reuse
            // issue next stage (DMA in flight during this step's MFMAs)
            if (ks < 15) {
                const _Float16* q1 = sp1 + (size_t)ic * KI * HDIM + (ks + 1) * 32;
                const _Float16* q2 = sp2 + (size_t)ic * KI * HDIM + (ks + 1) * 32;
                _Float16* t1 = lp1 + ((ks + 1) & 1) * 8192;
                _Float16* t2 = lp2 + ((ks + 1) & 1) * 8192;
                GL2LDS(q1, t1);
                GL2LDS(q2, t2);
            } else if (ic < IDIM / KI - 1) {
                const _Float16* q1 = sp1 + (size_t)(ic + 1) * KI * HDIM;
                const _Float16* q2 = sp2 + (size_t)(ic + 1) * KI * HDIM;
                GL2LDS(q1, lp1);   // next ic starts at buf0 (16 steps, even)
                GL2LDS(q2, lp2);
            }

            const char* bb = (const char*)BGU + (ks & 1) * 16384;
            f16x8 bgf = *(const f16x8*)(bb + bgOff);
            f16x8 buf_ = *(const f16x8*)(bb + buOff);
            const int k0b = (ks * 32 + bk) * 2;
#pragma unroll
            for (int mt = 0; mt < 4; ++mt) {
                const int m = mt * 16 + bn;
                int byte = m * 1024 + k0b;  byte ^= (m & 7) << 4;
                f16x8 af = *(const f16x8*)((const char*)A + byte);
                accG[mt] = __builtin_amdgcn_mfma_f32_16x16x32_f16(af, bgf, accG[mt], 0, 0, 0);
                accU[mt] = __builtin_amdgcn_mfma_f32_16x16x32_f16(af, buf_, accU[mt], 0, 0, 0);
            }
        }

        // bias + quick_gelu -> ACT[ic&1]
        char* actb = (char*)ACT + (ic & 1) * (BM * KI * 2);
        const int   gidx = e * 2 * IDIM + ic * KI + colu;
        const float bgv  = bgu[gidx];
        const float buv  = bgu[gidx + IDIM];
#pragma unroll
        for (int mt = 0; mt < 4; ++mt) {
#pragma unroll
            for (int r = 0; r < 4; ++r) {
                float g = accG[mt][r] + bgv;
                float u = accU[mt][r] + buv;
                float a = (u + 1.f) * g / (1.f + __expf(-1.702f * g));
                const int row = mt * 16 + ((lane >> 4) << 2) + r;
                int byte = row * 256 + colu * 2;  byte ^= (row & 7) << 4;
                *(_Float16*)(actb + byte) = (_Float16)a;
            }
        }
        __syncthreads();   // ACT visible (next-ic buf0 stage drains here too)

        // ------------------ phase 2: down-proj accumulate -------------------
        const _Float16* bdp = wd_t + ((size_t)(e * HDIM) + wv * 64) * IDIM;
#pragma unroll
        for (int ks = 0; ks < 4; ++ks) {
            const int kl = ks * 32 + bk;
            const int kg = ic * KI + kl;
            f16x8 bf[4];
#pragma unroll
            for (int nt = 0; nt < 4; ++nt)
                bf[nt] = *(const f16x8*)(bdp + (size_t)(nt * 16 + bn) * IDIM + kg);
#pragma unroll
            for (int mt = 0; mt < 4; ++mt) {
                const int m = mt * 16 + bn;
                int byte = m * 256 + kl * 2;  byte ^= (m & 7) << 4;
                f16x8 af = *(const f16x8*)((const char*)actb + byte);
#pragma unroll
                for (int nt = 0; nt < 4; ++nt)
                    accO[mt][nt] = __builtin_amdgcn_mfma_f32_16x16x32_f16(af, bf[nt], accO[mt][nt], 0, 0, 0);
            }
        }
        // no trailing barrier: next phase1 writes BGU (disjoint) and the
        // next ACT write targets the other ACT buffer
    }

    // ------------------ epilogue: weighted atomic scatter -------------------
    float bdv[4];
#pragma unroll
    for (int nt = 0; nt < 4; ++nt) bdv[nt] = bd[e * HDIM + wv * 64 + nt * 16 + bn];
#pragma unroll
    for (int mt = 0; mt < 4; ++mt) {
#pragma unroll
        for (int r = 0; r < 4; ++r) {
            const int m  = mt * 16 + ((lane >> 4) << 2) + r;
            const int tk = s_tok[m];
            if (tk < 0) continue;
            const float wgt = s_w[m];
            float* orow = out + (size_t)tk * HDIM + wv * 64 + bn;
#pragma unroll
            for (int nt = 0; nt < 4; ++nt)
                atomicAdd(orow + nt * 16, (accO[mt][nt][r] + bdv[nt]) * wgt);
        }
    }
}

// ---------------------------------------------------------------------------
extern "C" void kernel_launch(void* const* d_in, const int* in_sizes, int n_in,
                              void* d_out, int out_size, void* d_ws, size_t ws_size,
                              hipStream_t stream)
{
    const float* x   = (const float*)d_in[0];
    const float* rw  = (const float*)d_in[1];
    const float* rb  = (const float*)d_in[2];
    const float* wgu = (const float*)d_in[3];
    const float* bgu = (const float*)d_in[4];
    const float* wd  = (const float*)d_in[5];
    const float* bd  = (const float*)d_in[6];
    float* out = (float*)d_out;

    char* ws = (char*)d_ws;
    size_t o = 0;
    int*   cnt  = (int*)(ws + o);   o += 256;
    int*   btok = (int*)(ws + o);   o += (size_t)NEXP * T_TOK * 4;
    float* bwp  = (float*)(ws + o); o += (size_t)NEXP * T_TOK * 4;
    _Float16* wgu_t = (_Float16*)(ws + o); o += (size_t)NEXP * 2 * IDIM * HDIM * 2;
    _Float16* wd_t  = (_Float16*)(ws + o); o += (size_t)NEXP * HDIM * IDIM * 2;

    hipMemsetAsync(cnt, 0, 256, stream);
    hipMemsetAsync(out, 0, (size_t)out_size * 4, stream);

    transpose_cvt<HDIM, 2 * IDIM><<<dim3(2 * IDIM / 32, HDIM / 32, NEXP), 256, 0, stream>>>(wgu, wgu_t);
    transpose_cvt<IDIM, HDIM><<<dim3(HDIM / 32, IDIM / 32, NEXP), 256, 0, stream>>>(wd, wd_t);
    router_kernel<<<T_TOK / 64, 256, 0, stream>>>(x, rw, rb, cnt, btok, bwp);
    moe_kernel<<<dim3((T_TOK / BM) * NEXP), 512, 0, stream>>>(
        x, wgu_t, bgu, wd_t, bd, cnt, btok, bwp, out);
}

// Round 8
// 687.407 us; speedup vs baseline: 2.0725x; 1.0884x over previous
//
#include <hip/hip_runtime.h>

#define T_TOK 32768
#define HDIM  512
#define IDIM  1024
#define NEXP  8
#define BM    64
#define KI    128

typedef float    f32x4 __attribute__((ext_vector_type(4)));
typedef _Float16 f16x8 __attribute__((ext_vector_type(8)));
typedef _Float16 f16x4 __attribute__((ext_vector_type(4)));

// global_load_lds, 16B per lane, LDS dest = wave-uniform base + lane*16
#define GL2LDS(gp, lp)                                                        \
    __builtin_amdgcn_global_load_lds(                                         \
        (const __attribute__((address_space(1))) void*)(gp),                  \
        (__attribute__((address_space(3))) void*)(lp), 16, 0, 0)

// LDS-only drained barrier: lgkmcnt(0) + raw s_barrier. Leaves global_load_lds
// (vmcnt) traffic in flight — the entire point of the counted pipeline.
#define LGKM_BAR()                                                            \
    do {                                                                      \
        asm volatile("s_waitcnt lgkmcnt(0)" ::: "memory");                    \
        __builtin_amdgcn_s_barrier();                                         \
    } while (0)

// ---------------------------------------------------------------------------
// Router: logits = x @ rw + rb ; top-2 ; softmax over the 2 ; bucket append.
// Block-aggregated bucket atomics (LDS counts, 8 global atomics per block).
// ---------------------------------------------------------------------------
__global__ __launch_bounds__(256) void router_kernel(
    const float* __restrict__ x, const float* __restrict__ rw,
    const float* __restrict__ rb, int* __restrict__ cnt,
    int* __restrict__ btok, float* __restrict__ bw)
{
    __shared__ float Wl[HDIM * NEXP];
    __shared__ float xc[64 * 133];
    __shared__ float part[4 * 64 * 8];
    __shared__ int   bcnt[NEXP];
    __shared__ int   sbase[NEXP];

    const int tid = threadIdx.x;
    const int t0  = blockIdx.x * 64;

    if (tid < NEXP) bcnt[tid] = 0;

    for (int j = tid; j < HDIM * NEXP / 4; j += 256)
        ((float4*)Wl)[j] = ((const float4*)rw)[j];

    const int tl = tid & 63;
    const int q  = tid >> 6;

    float acc[8];
#pragma unroll
    for (int e = 0; e < 8; ++e) acc[e] = 0.f;

    for (int hc = 0; hc < 4; ++hc) {
        __syncthreads();
        for (int j = tid; j < 64 * 128 / 4; j += 256) {
            int row = j >> 5;
            int col = (j & 31) * 4;
            float4 v = *(const float4*)(x + (size_t)(t0 + row) * HDIM + hc * 128 + col);
            float* d = &xc[row * 133 + col];
            d[0] = v.x; d[1] = v.y; d[2] = v.z; d[3] = v.w;
        }
        __syncthreads();
#pragma unroll
        for (int hh = 0; hh < 32; ++hh) {
            int h = q * 32 + hh;
            float xv = xc[tl * 133 + h];
            const float* wrow = &Wl[(hc * 128 + h) * 8];
#pragma unroll
            for (int e = 0; e < 8; ++e) acc[e] += xv * wrow[e];
        }
    }
#pragma unroll
    for (int e = 0; e < 8; ++e) part[(q * 64 + tl) * 8 + e] = acc[e];
    __syncthreads();

    int e0 = 0, e1 = 0, l0 = 0, l1 = 0;
    float w0 = 0.f, w1 = 0.f;
    if (tid < 64) {
        float lg[8];
#pragma unroll
        for (int e = 0; e < 8; ++e)
            lg[e] = part[(0 * 64 + tid) * 8 + e] + part[(1 * 64 + tid) * 8 + e] +
                    part[(2 * 64 + tid) * 8 + e] + part[(3 * 64 + tid) * 8 + e] + rb[e];
#pragma unroll
        for (int e = 1; e < 8; ++e) if (lg[e] > lg[e0]) e0 = e;
        e1 = (e0 == 0) ? 1 : 0;
#pragma unroll
        for (int e = 0; e < 8; ++e) if (e != e0 && lg[e] > lg[e1]) e1 = e;
        float z = __expf(lg[e1] - lg[e0]);
        w0 = 1.f / (1.f + z);
        w1 = z * w0;
        l0 = atomicAdd(&bcnt[e0], 1);
        l1 = atomicAdd(&bcnt[e1], 1);
    }
    __syncthreads();
    if (tid < NEXP) sbase[tid] = atomicAdd(&cnt[tid], bcnt[tid]);
    __syncthreads();
    if (tid < 64) {
        int t  = t0 + tid;
        int s0 = sbase[e0] + l0;
        btok[e0 * T_TOK + s0] = t;  bw[e0 * T_TOK + s0] = w0;
        int s1 = sbase[e1] + l1;
        btok[e1 * T_TOK + s1] = t;  bw[e1 * T_TOK + s1] = w1;
    }
}

// ---------------------------------------------------------------------------
// Transpose + fp32->fp16 convert: src [E][R][C] f32 -> dst [E][C][R] f16
// ---------------------------------------------------------------------------
template <int R, int C>
__global__ __launch_bounds__(256) void transpose_cvt(
    const float* __restrict__ src, _Float16* __restrict__ dst)
{
    __shared__ float tile[32][33];
    const int e  = blockIdx.z;
    const int rb = blockIdx.y * 32, cb = blockIdx.x * 32;
    const int t  = threadIdx.x;
    {
        const int lr = t >> 3, lc = (t & 7) * 4;
        float4 v = *(const float4*)(src + ((size_t)e * R + rb + lr) * C + cb + lc);
        tile[lr][lc + 0] = v.x; tile[lr][lc + 1] = v.y;
        tile[lr][lc + 2] = v.z; tile[lr][lc + 3] = v.w;
    }
    __syncthreads();
    {
        const int c = t >> 3, r4 = (t & 7) * 4;
        f16x4 h;
        h[0] = (_Float16)tile[r4 + 0][c];
        h[1] = (_Float16)tile[r4 + 1][c];
        h[2] = (_Float16)tile[r4 + 2][c];
        h[3] = (_Float16)tile[r4 + 3][c];
        *(f16x4*)(dst + ((size_t)e * C + cb + c) * R + rb + r4) = h;
    }
}

// ---------------------------------------------------------------------------
// Fused expert kernel — T4 counted-vmcnt pipeline in phase 1.
// Block = (expert e = bid&7 -> XCD e, 64 bucket rows), 512 threads, 8 waves.
// Phase1: 16 K-steps of K=32 per ic; gate+up weight tile (16 KB) for step s
// staged 3 AHEAD via global_load_lds into BGU[s&3] (4 x 16 KB). Per step:
//   s_waitcnt vmcnt(4)      // oldest stage landed (2 loads/stage, 2 allowed)
//   raw s_barrier           // NO compiler drain — younger stages stay in flight
//   issue stage s+3; ds_read frags; setprio(1); 8 MFMA; setprio(0)
// Buffer safety: buf[(s+3)&3] was read at step s-1; those reads completed
// before their waves passed barrier s (lgkm-consumption by MFMA).
// Phase boundaries use LGKM_BAR (LDS-only drain) so DMA survives them.
// ---------------------------------------------------------------------------
__global__ __launch_bounds__(512) void moe_kernel(
    const float* __restrict__ x,
    const _Float16* __restrict__ wgu_t,   // [E][2I][H]
    const float* __restrict__ bgu,        // [E][2I]
    const _Float16* __restrict__ wd_t,    // [E][H][I]
    const float* __restrict__ bd,         // [E][H]
    const int* __restrict__ cnt,
    const int* __restrict__ btok,
    const float* __restrict__ bw,
    float* __restrict__ out)
{
    const int bid = blockIdx.x;
    const int e   = bid & 7;              // XCD affinity
    const int m0  = (bid >> 3) * BM;
    const int n_e = cnt[e];
    if (m0 >= n_e) return;

    __shared__ __align__(16) _Float16 A[BM * HDIM];     // 64 KB, XOR-swizzled
    __shared__ __align__(16) _Float16 BGU[4 * 8192];    // 4 x 16 KB stage bufs
    __shared__ __align__(16) _Float16 ACT[BM * KI];     // 16 KB, swizzled
    __shared__ int   s_tok[BM];
    __shared__ float s_w[BM];

    const int tid  = threadIdx.x;
    const int lane = tid & 63;
    const int wv   = tid >> 6;
    const int bn   = lane & 15;
    const int bk   = (lane >> 4) * 8;

    // --- per-thread stage source decode (two 16B granules per thread) ---
    // dest byte d (within 16 KB buffer) -> unswizzled u -> (colpair, dir, k)
    const int d1 = tid * 16;
    const int u1 = d1 ^ (((d1 >> 7) & 7) << 4);
    const int d2 = d1 + 8192;
    const int u2 = d2 ^ (((d2 >> 7) & 7) << 4);
    const _Float16* wguE = wgu_t + (size_t)e * 2 * IDIM * HDIM;
    const _Float16* sp1  = wguE + ((size_t)(((u1 >> 6) & 1) * IDIM + (u1 >> 7))) * HDIM + ((u1 & 63) >> 1);
    const _Float16* sp2  = wguE + ((size_t)(((u2 >> 6) & 1) * IDIM + (u2 >> 7))) * HDIM + ((u2 & 63) >> 1);

    if (tid < BM) {
        int idx = m0 + tid;
        if (idx < n_e) { s_tok[tid] = btok[e * T_TOK + idx]; s_w[tid] = bw[e * T_TOK + idx]; }
        else           { s_tok[tid] = -1;                    s_w[tid] = 0.f; }
    }
    LGKM_BAR();                            // s_tok visible

    // prologue: stages s=0,1,2 into buf 0,1,2 (complete during the gather)
#pragma unroll
    for (int s = 0; s < 3; ++s) {
        const size_t off = (size_t)(s & 15) * 32;
        _Float16* t1 = BGU + s * 8192 + tid * 8;
        GL2LDS(sp1 + off, t1);
        GL2LDS(sp2 + off, t1 + 4096);
    }

    // ---- gather x rows -> fp16 swizzled LDS (8 threads per row) ----
    {
        const int r  = tid >> 3;
        const int tk = s_tok[r];
#pragma unroll
        for (int j = 0; j < 8; ++j) {
            const int c = ((tid & 7) + j * 8) * 8;
            float4 f0, f1;
            if (tk >= 0) {
                const float4* p = (const float4*)(x + (size_t)tk * HDIM + c);
                f0 = p[0]; f1 = p[1];
            } else { f0 = make_float4(0, 0, 0, 0); f1 = f0; }
            f16x8 h;
            h[0] = (_Float16)f0.x; h[1] = (_Float16)f0.y;
            h[2] = (_Float16)f0.z; h[3] = (_Float16)f0.w;
            h[4] = (_Float16)f1.x; h[5] = (_Float16)f1.y;
            h[6] = (_Float16)f1.z; h[7] = (_Float16)f1.w;
            int byte = r * 1024 + c * 2;  byte ^= (r & 7) << 4;
            *(f16x8*)((char*)A + byte) = h;
        }
    }
    LGKM_BAR();                            // A visible

    f32x4 accO[4][4];
#pragma unroll
    for (int mt = 0; mt < 4; ++mt)
#pragma unroll
        for (int nt = 0; nt < 4; ++nt)
#pragma unroll
            for (int r = 0; r < 4; ++r) accO[mt][nt][r] = 0.f;

    // B-frag read byte offsets (within a 16 KB stage buffer), fixed per thread
    const int colu = wv * 16 + bn;
    const int sw   = (colu & 7) << 4;
    const int bgOff = colu * 128 + ((bk * 2) ^ sw);          // gate frag
    const int buOff = colu * 128 + ((64 + bk * 2) ^ sw);     // up frag

    for (int ic = 0; ic < IDIM / KI; ++ic) {
        // bias loads issued early; consumed ~16 steps later
        const int   gidx = e * 2 * IDIM + ic * KI + colu;
        const float bgv  = bgu[gidx];
        const float buv  = bgu[gidx + IDIM];

        f32x4 accG[4], accU[4];
#pragma unroll
        for (int mt = 0; mt < 4; ++mt)
#pragma unroll
            for (int r = 0; r < 4; ++r) { accG[mt][r] = 0.f; accU[mt][r] = 0.f; }

        // ---------- phase 1: counted-vmcnt staged K-loop ----------
#pragma unroll
        for (int ks = 0; ks < 16; ++ks) {
            asm volatile("s_waitcnt vmcnt(4)" ::: "memory");
            __builtin_amdgcn_s_barrier();

            const int s3 = ic * 16 + ks + 3;           // stage 3 ahead
            if (s3 < (IDIM / KI) * 16) {
                const size_t off = (size_t)(s3 >> 4) * KI * HDIM + (size_t)(s3 & 15) * 32;
                _Float16* t1 = BGU + ((ks + 3) & 3) * 8192 + tid * 8;  // (s3&3)==((ks+3)&3)
                GL2LDS(sp1 + off, t1);
                GL2LDS(sp2 + off, t1 + 4096);
            }

            const char* bb = (const char*)BGU + (ks & 3) * 16384;
            f16x8 bgf  = *(const f16x8*)(bb + bgOff);
            f16x8 buf_ = *(const f16x8*)(bb + buOff);
            const int k0b = (ks * 32 + bk) * 2;
            __builtin_amdgcn_s_setprio(1);
#pragma unroll
            for (int mt = 0; mt < 4; ++mt) {
                const int m = mt * 16 + bn;
                int byte = m * 1024 + k0b;  byte ^= (m & 7) << 4;
                f16x8 af = *(const f16x8*)((const char*)A + byte);
                accG[mt] = __builtin_amdgcn_mfma_f32_16x16x32_f16(af, bgf, accG[mt], 0, 0, 0);
                accU[mt] = __builtin_amdgcn_mfma_f32_16x16x32_f16(af, buf_, accU[mt], 0, 0, 0);
            }
            __builtin_amdgcn_s_setprio(0);
        }

        // bias + quick_gelu -> ACT (single buffer; the 16 phase-1 barriers
        // order phase2(ic-1) reads vs this write)
#pragma unroll
        for (int mt = 0; mt < 4; ++mt) {
#pragma unroll
            for (int r = 0; r < 4; ++r) {
                float g = accG[mt][r] + bgv;
                float u = accU[mt][r] + buv;
                float a = (u + 1.f) * g / (1.f + __expf(-1.702f * g));
                const int row = mt * 16 + ((lane >> 4) << 2) + r;
                int byte = row * 256 + colu * 2;  byte ^= (row & 7) << 4;
                *(_Float16*)((char*)ACT + byte) = (_Float16)a;
            }
        }
        LGKM_BAR();                        // ACT visible; DMA stays in flight

        // ---------- phase 2: down-proj accumulate ----------
        const _Float16* bdp = wd_t + ((size_t)(e * HDIM) + wv * 64) * IDIM;
#pragma unroll
        for (int ks = 0; ks < 4; ++ks) {
            const int kl = ks * 32 + bk;
            const int kg = ic * KI + kl;
            f16x8 bf[4];
#pragma unroll
            for (int nt = 0; nt < 4; ++nt)
                bf[nt] = *(const f16x8*)(bdp + (size_t)(nt * 16 + bn) * IDIM + kg);
            f16x8 af2[4];
#pragma unroll
            for (int mt = 0; mt < 4; ++mt) {
                const int m = mt * 16 + bn;
                int byte = m * 256 + kl * 2;  byte ^= (m & 7) << 4;
                af2[mt] = *(const f16x8*)((const char*)ACT + byte);
            }
            __builtin_amdgcn_s_setprio(1);
#pragma unroll
            for (int mt = 0; mt < 4; ++mt)
#pragma unroll
                for (int nt = 0; nt < 4; ++nt)
                    accO[mt][nt] = __builtin_amdgcn_mfma_f32_16x16x32_f16(
                        af2[mt], bf[nt], accO[mt][nt], 0, 0, 0);
            __builtin_amdgcn_s_setprio(0);
        }
        // no trailing barrier: next phase1's step-0 barrier orders ACT reuse
    }

    // ------------------ epilogue: weighted atomic scatter -------------------
    float bdv[4];
#pragma unroll
    for (int nt = 0; nt < 4; ++nt) bdv[nt] = bd[e * HDIM + wv * 64 + nt * 16 + bn];
#pragma unroll
    for (int mt = 0; mt < 4; ++mt) {
#pragma unroll
        for (int r = 0; r < 4; ++r) {
            const int m  = mt * 16 + ((lane >> 4) << 2) + r;
            const int tk = s_tok[m];
            if (tk < 0) continue;
            const float wgt = s_w[m];
            float* orow = out + (size_t)tk * HDIM + wv * 64 + bn;
#pragma unroll
            for (int nt = 0; nt < 4; ++nt)
                atomicAdd(orow + nt * 16, (accO[mt][nt][r] + bdv[nt]) * wgt);
        }
    }
}

// ---------------------------------------------------------------------------
extern "C" void kernel_launch(void* const* d_in, const int* in_sizes, int n_in,
                              void* d_out, int out_size, void* d_ws, size_t ws_size,
                              hipStream_t stream)
{
    const float* x   = (const float*)d_in[0];
    const float* rw  = (const float*)d_in[1];
    const float* rb  = (const float*)d_in[2];
    const float* wgu = (const float*)d_in[3];
    const float* bgu = (const float*)d_in[4];
    const float* wd  = (const float*)d_in[5];
    const float* bd  = (const float*)d_in[6];
    float* out = (float*)d_out;

    char* ws = (char*)d_ws;
    size_t o = 0;
    int*   cnt  = (int*)(ws + o);   o += 256;
    int*   btok = (int*)(ws + o);   o += (size_t)NEXP * T_TOK * 4;
    float* bwp  = (float*)(ws + o); o += (size_t)NEXP * T_TOK * 4;
    _Float16* wgu_t = (_Float16*)(ws + o); o += (size_t)NEXP * 2 * IDIM * HDIM * 2;
    _Float16* wd_t  = (_Float16*)(ws + o); o += (size_t)NEXP * HDIM * IDIM * 2;

    hipMemsetAsync(cnt, 0, 256, stream);
    hipMemsetAsync(out, 0, (size_t)out_size * 4, stream);

    transpose_cvt<HDIM, 2 * IDIM><<<dim3(2 * IDIM / 32, HDIM / 32, NEXP), 256, 0, stream>>>(wgu, wgu_t);
    transpose_cvt<IDIM, HDIM><<<dim3(HDIM / 32, IDIM / 32, NEXP), 256, 0, stream>>>(wd, wd_t);
    router_kernel<<<T_TOK / 64, 256, 0, stream>>>(x, rw, rb, cnt, btok, bwp);
    moe_kernel<<<dim3((T_TOK / BM) * NEXP), 512, 0, stream>>>(
        x, wgu_t, bgu, wd_t, bd, cnt, btok, bwp, out);
}